// Round 6
// baseline (860.276 us; speedup 1.0000x reference)
//
#include <hip/hip_runtime.h>
#include <math.h>

#define BATCH 256
#define SEQ   2048
#define HID   128
#define NTHR  512
#define VOCAB 50000

typedef _Float16 v2h __attribute__((ext_vector_type(2)));
typedef _Float16 v8h __attribute__((ext_vector_type(8)));
typedef float    v4f __attribute__((ext_vector_type(4)));

template<int CTRL>
__device__ __forceinline__ float dpp_movf(float x) {
    return __builtin_bit_cast(float,
        __builtin_amdgcn_update_dpp(0, __builtin_bit_cast(int, x),
                                    CTRL, 0xF, 0xF, false));
}
__device__ __forceinline__ float quad_reduce(float x) {
    x += dpp_movf<0xB1>(x);   // + lane^1
    x += dpp_movf<0x4E>(x);   // + lane^2
    return x;
}
__device__ __forceinline__ float fast_rcp(float x) { return __builtin_amdgcn_rcpf(x); }
__device__ __forceinline__ float fast_tanh(float z) {
    float e = __expf(2.0f * z);
    return 1.0f - 2.0f * fast_rcp(e + 1.0f);
}
__device__ __forceinline__ float dot2(v2h a, v2h b, float c) {
    return __builtin_amdgcn_fdot2(a, b, c, false);
}
#define BCH(u) __builtin_bit_cast(v2h, (u))
#define BC8(u) __builtin_bit_cast(v8h, (u))

// ---------------- Y = emb @ W_ih[0] + b[0]  (f16 out) ----------------
__global__ __launch_bounds__(NTHR, 2) void emb_proj_kernel(
    const float* __restrict__ emb,   // [VOCAB, 128]
    const float* __restrict__ W_ih,  // [2, 128, 128] (layer 0 used)
    const float* __restrict__ bias,  // [2, 128]
    _Float16*    __restrict__ Y)     // [VOCAB, 128]
{
    const int tid  = threadIdx.x;
    const int wave = tid >> 6;
    const int lane = tid & 63;
    const int j    = wave * 16 + (lane >> 2);
    const int q    = lane & 3;

    __shared__ __align__(16) _Float16 xr[HID];

    v2h w[16];
#pragma unroll
    for (int i = 0; i < 16; ++i) {
        const int k = q * 32 + 2 * i;
        w[i] = v2h{(_Float16)W_ih[k * HID + j], (_Float16)W_ih[(k + 1) * HID + j]};
    }
    const float bj = bias[j];
    const float4* embf4 = (const float4*)emb;

    for (int r = blockIdx.x; r < VOCAB; r += gridDim.x) {
        if (tid < 32) {
            float4 v = embf4[(size_t)r * 32 + tid];
            uint a01 = __builtin_bit_cast(uint, __builtin_amdgcn_cvt_pkrtz(v.x, v.y));
            uint a23 = __builtin_bit_cast(uint, __builtin_amdgcn_cvt_pkrtz(v.z, v.w));
            ((uint2*)&xr[0])[tid] = uint2{a01, a23};
        }
        __syncthreads();
        const uint4* xp = (const uint4*)&xr[0] + q * 4;
        float acc = 0.f;
#pragma unroll
        for (int i = 0; i < 4; ++i) {
            const uint4 xu = xp[i];
            acc = dot2(BCH(xu.x), w[4*i+0], acc);
            acc = dot2(BCH(xu.y), w[4*i+1], acc);
            acc = dot2(BCH(xu.z), w[4*i+2], acc);
            acc = dot2(BCH(xu.w), w[4*i+3], acc);
        }
        acc = quad_reduce(acc) + bj;
        if (q == 0) Y[(size_t)r * HID + j] = (_Float16)acc;
        __syncthreads();
    }
}

// ---------------- recurrent kernel: MFMA phases, depth-1 accumulators ----------------
// Wave w owns output j-tile [16w, 16w+16) of BOTH layers.
// Phase ph computes h0(ph) = tanh(Y[tok(ph)] + Whh0 h0(ph-1))  and
//                  h1(ph-1) = tanh(Wih1 h0(ph-1) + Whh1 h1(ph-2) + b1).
// 12 MFMAs per phase issue into 12 INDEPENDENT accumulators (dep chain = 1),
// reduced by a short scalar add tree. C/D row 0 = .x of lanes 0..15.
__global__ __launch_bounds__(NTHR, 2) void rnn_mfma_kernel(
    const int*      __restrict__ x,        // [B, T]
    const int*      __restrict__ lengths,  // [B]
    const _Float16* __restrict__ Y,        // [VOCAB, 128] = emb@Wih0 + b0
    const float*    __restrict__ W_ih,     // [2, 128, 128] (layer 1 used)
    const float*    __restrict__ W_hh,     // [2, 128, 128]
    const float*    __restrict__ bias,     // [2, 128] (layer 1 used)
    const float*    __restrict__ cls_w,    // [128]
    const float*    __restrict__ cls_b,    // [1]
    float*          __restrict__ out)      // [B]
{
    const int b    = blockIdx.x;
    const int tid  = threadIdx.x;
    const int wave = tid >> 6;
    const int lane = tid & 63;
    const int kg   = lane >> 4;            // k-group 0..3 (8 f16 each)
    const int jcol = wave * 16 + (lane & 15);

    __shared__ int xids[SEQ];                        // 8 KB
    __shared__ __align__(16) _Float16 h0h[2][HID];
    __shared__ __align__(16) _Float16 h1h[2][HID];
    __shared__ __align__(16) float    red[HID];

    const int len   = lengths[b];
    const int lenm1 = len - 1;
    const float LOG2E2 = 2.88539008177793f;          // 2*log2(e)

    for (int i = tid; i < SEQ; i += NTHR) xids[i] = x[b * SEQ + i];
    if (tid < HID) {
        h0h[0][tid] = (_Float16)0.f; h0h[1][tid] = (_Float16)0.f;
        h1h[0][tid] = (_Float16)0.f; h1h[1][tid] = (_Float16)0.f;
    }

    // static B-fragments: B[k][n] slot e at lane (16*kg + n): k = 32kt+8kg+e
    v8h Bhh0[4], Bih1[4], Bhh1[4];
#pragma unroll
    for (int kt = 0; kt < 4; ++kt) {
        v8h b0v, b1v, b2v;
#pragma unroll
        for (int e = 0; e < 8; ++e) {
            const int k = kt * 32 + kg * 8 + e;
            b0v[e] = (_Float16)W_hh[k * HID + jcol];
            b1v[e] = (_Float16)W_ih[HID * HID + k * HID + jcol];
            b2v[e] = (_Float16)W_hh[HID * HID + k * HID + jcol];
        }
        Bhh0[kt] = b0v; Bih1[kt] = b1v; Bhh1[kt] = b2v;
    }
    const float b1K = bias[HID + jcol] * LOG2E2;     // pre-scaled for exp2 path

    __syncthreads();                                 // xids + zeroed h visible

    // z-ring (depth 2): layer-0 input gather Y[tok][jcol]
    _Float16 zA = Y[(size_t)xids[0] * HID + jcol];
    _Float16 zB = Y[(size_t)xids[min(1, lenm1)] * HID + jcol];

    int ph = 0, pf = 0;

    // tanh(z) with pre-scaled argument zK = z*2*log2(e): 1 - 2/(exp2(zK)+1)
#define TANH_PRE(ZK) (1.0f - 2.0f * fast_rcp(__builtin_amdgcn_exp2f(ZK) + 1.0f))

#define DO_PHASE(RD, WR, ZREG)                                              \
    {                                                                       \
        const uint4* h0p = (const uint4*)&h0h[RD][0];                       \
        const uint4* h1p = (const uint4*)&h1h[RD][0];                       \
        v8h A0[4], A1[4];                                                   \
        _Pragma("unroll")                                                   \
        for (int kt = 0; kt < 4; ++kt) {                                    \
            A0[kt] = BC8(h0p[kt * 4 + kg]);                                 \
            A1[kt] = BC8(h1p[kt * 4 + kg]);                                 \
        }                                                                   \
        const float zcK = (float)ZREG * LOG2E2;      /* off critical path */\
        {                                                                   \
            const int tn = xids[min(ph + 2, lenm1)];                        \
            ZREG = Y[(size_t)tn * HID + jcol];                              \
        }                                                                   \
        v4f c0[4], cA[4], cB[4];                                            \
        _Pragma("unroll")                                                   \
        for (int kt = 0; kt < 4; ++kt) {                                    \
            c0[kt] = __builtin_amdgcn_mfma_f32_16x16x32_f16(A0[kt], Bhh0[kt], v4f{0,0,0,0}, 0, 0, 0); \
            cA[kt] = __builtin_amdgcn_mfma_f32_16x16x32_f16(A0[kt], Bih1[kt], v4f{0,0,0,0}, 0, 0, 0); \
            cB[kt] = __builtin_amdgcn_mfma_f32_16x16x32_f16(A1[kt], Bhh1[kt], v4f{0,0,0,0}, 0, 0, 0); \
        }                                                                   \
        const float s0 = (c0[0].x + c0[1].x) + (c0[2].x + c0[3].x);         \
        const float s1 = ((cA[0].x + cA[1].x) + (cA[2].x + cA[3].x))        \
                       + ((cB[0].x + cB[1].x) + (cB[2].x + cB[3].x));       \
        const float t0 = TANH_PRE(__builtin_fmaf(s0, LOG2E2, zcK));         \
        const float t1 = TANH_PRE(__builtin_fmaf(s1, LOG2E2, b1K));         \
        if (kg == 0) {                                                      \
            if (ph < len) h0h[WR][jcol] = (_Float16)t0;                     \
            if (ph >= 1)  h1h[WR][jcol] = (_Float16)t1;                     \
        }                                                                   \
        __syncthreads();                                                    \
    }

    for (;;) {
        DO_PHASE(0, 1, zA)
        ++ph;
        if (ph > len) { pf = 1; break; }
        DO_PHASE(1, 0, zB)
        ++ph;
        if (ph > len) { pf = 0; break; }
    }
#undef DO_PHASE
#undef TANH_PRE

    // classifier: out[b] = sigmoid(h1(len-1) . cls_w + cls_b)
    if (tid < HID) red[tid] = (float)h1h[pf][tid] * cls_w[tid];
    __syncthreads();
    if (tid == 0) {
        float s = 0.f;
        for (int i = 0; i < HID; ++i) s += red[i];
        s += cls_b[0];
        out[b] = fast_rcp(1.0f + __expf(-s));
    }
}

extern "C" void kernel_launch(void* const* d_in, const int* in_sizes, int n_in,
                              void* d_out, int out_size, void* d_ws, size_t ws_size,
                              hipStream_t stream) {
    const int*   x       = (const int*)  d_in[0];
    const int*   lengths = (const int*)  d_in[1];
    const float* emb     = (const float*)d_in[2];
    const float* W_ih    = (const float*)d_in[3];
    const float* W_hh    = (const float*)d_in[4];
    const float* bias    = (const float*)d_in[5];
    const float* cls_w   = (const float*)d_in[6];
    const float* cls_b   = (const float*)d_in[7];
    float*       out     = (float*)      d_out;

    _Float16* Yws = (_Float16*)d_ws;     // 50000*128*2 B = 12.8 MB

    emb_proj_kernel<<<2048, NTHR, 0, stream>>>(emb, W_ih, bias, Yws);
    rnn_mfma_kernel<<<BATCH, NTHR, 0, stream>>>(
        x, lengths, Yws, W_ih, W_hh, bias, cls_w, cls_b, out);
}

// Round 7
// 818.121 us; speedup vs baseline: 1.0515x; 1.0515x over previous
//
#include <hip/hip_runtime.h>
#include <math.h>

#define BATCH 256
#define SEQ   2048
#define HID   128
#define NTHR  256
#define VOCAB 50000

typedef _Float16 v2h __attribute__((ext_vector_type(2)));

template<int CTRL>
__device__ __forceinline__ float dpp_movf(float x) {
    return __builtin_bit_cast(float,
        __builtin_amdgcn_update_dpp(0, __builtin_bit_cast(int, x),
                                    CTRL, 0xF, 0xF, false));
}
__device__ __forceinline__ float quad_reduce(float x) {
    x += dpp_movf<0xB1>(x);   // + lane^1
    x += dpp_movf<0x4E>(x);   // + lane^2
    return x;                 // full quad sum in all 4 lanes
}
__device__ __forceinline__ float fast_rcp(float x) { return __builtin_amdgcn_rcpf(x); }
__device__ __forceinline__ float dot2(v2h a, v2h b, float c) {
    return __builtin_amdgcn_fdot2(a, b, c, false);   // v_dot2_f32_f16
}
#define BCH(u) __builtin_bit_cast(v2h, (u))

// ---------------- Y = emb @ W_ih[0] + b[0]  (f16 out) ----------------
__global__ __launch_bounds__(512, 2) void emb_proj_kernel(
    const float* __restrict__ emb,   // [VOCAB, 128]
    const float* __restrict__ W_ih,  // [2, 128, 128] (layer 0 used)
    const float* __restrict__ bias,  // [2, 128]
    _Float16*    __restrict__ Y)     // [VOCAB, 128]
{
    const int tid  = threadIdx.x;
    const int wave = tid >> 6;
    const int lane = tid & 63;
    const int j    = wave * 16 + (lane >> 2);
    const int q    = lane & 3;

    __shared__ __align__(16) _Float16 xr[HID];

    v2h w[16];
#pragma unroll
    for (int i = 0; i < 16; ++i) {
        const int k = q * 32 + 2 * i;
        w[i] = v2h{(_Float16)W_ih[k * HID + j], (_Float16)W_ih[(k + 1) * HID + j]};
    }
    const float bj = bias[j];
    const float4* embf4 = (const float4*)emb;

    for (int r = blockIdx.x; r < VOCAB; r += gridDim.x) {
        if (tid < 32) {
            float4 v = embf4[(size_t)r * 32 + tid];
            uint a01 = __builtin_bit_cast(uint, __builtin_amdgcn_cvt_pkrtz(v.x, v.y));
            uint a23 = __builtin_bit_cast(uint, __builtin_amdgcn_cvt_pkrtz(v.z, v.w));
            ((uint2*)&xr[0])[tid] = uint2{a01, a23};
        }
        __syncthreads();
        const uint4* xp = (const uint4*)&xr[0] + q * 4;
        float acc = 0.f;
#pragma unroll
        for (int i = 0; i < 4; ++i) {
            const uint4 xu = xp[i];
            acc = dot2(BCH(xu.x), w[4*i+0], acc);
            acc = dot2(BCH(xu.y), w[4*i+1], acc);
            acc = dot2(BCH(xu.z), w[4*i+2], acc);
            acc = dot2(BCH(xu.w), w[4*i+3], acc);
        }
        acc = quad_reduce(acc) + bj;
        if (q == 0) Y[(size_t)r * HID + j] = (_Float16)acc;
        __syncthreads();
    }
}

// ---------------- recurrent kernel: dot2 VALU, J=2 cols/thread ----------------
// 4 waves. Thread (jg = wave*16 + (lane>>2) in [0,64), q = lane&3) owns
// columns {2jg, 2jg+1} and k-slice [32q, 32q+32) of all 3 matvecs
// (Whh0, Wih1, Whh1) -- 96 f16-pair weight VGPRs.
// Phase ph: h0(ph) = tanh(Y[tok(ph)] + Whh0 h0(ph-1)),
//           h1(ph-1) = tanh(Wih1 h0(ph-1) + Whh1 h1(ph-2) + b1).
// 96 dot2 into 6 independent accumulators; quad DPP butterfly gives full
// 128-k sums to all 4 quad lanes; lane q takes task (jm=q&1, layer=q>>1):
// one tanh + one b16 LDS write. One barrier per phase.
__global__ __launch_bounds__(NTHR, 1) void rnn_dot2_kernel(
    const int*      __restrict__ x,        // [B, T]
    const int*      __restrict__ lengths,  // [B]
    const _Float16* __restrict__ Y,        // [VOCAB, 128] = emb@Wih0 + b0
    const float*    __restrict__ W_ih,     // [2, 128, 128] (layer 1 used)
    const float*    __restrict__ W_hh,     // [2, 128, 128]
    const float*    __restrict__ bias,     // [2, 128] (layer 1 used)
    const float*    __restrict__ cls_w,    // [128]
    const float*    __restrict__ cls_b,    // [1]
    float*          __restrict__ out)      // [B]
{
    const int b    = blockIdx.x;
    const int tid  = threadIdx.x;
    const int wave = tid >> 6;
    const int lane = tid & 63;
    const int jg   = wave * 16 + (lane >> 2);   // [0,64): owns j = 2jg, 2jg+1
    const int q    = lane & 3;                  // k-quarter [32q, 32q+32)
    const int jm   = lane & 1;                  // task column select
    const int isl1 = (lane >> 1) & 1;           // task layer select
    const int jt   = 2 * jg + jm;               // this lane's task column

    __shared__ int xids[SEQ];                        // 8 KB
    __shared__ __align__(16) _Float16 h0h[2][HID];
    __shared__ __align__(16) _Float16 h1h[2][HID];
    __shared__ __align__(16) float    red[HID];

    const int len   = lengths[b];
    const int lenm1 = len - 1;
    const float LOG2E2 = 2.88539008177793f;          // 2*log2(e)

    for (int i = tid; i < SEQ; i += NTHR) xids[i] = x[b * SEQ + i];
    if (tid < HID) {
        h0h[0][tid] = (_Float16)0.f; h0h[1][tid] = (_Float16)0.f;
        h1h[0][tid] = (_Float16)0.f; h1h[1][tid] = (_Float16)0.f;
    }

    // weights -> VGPRs: pack along k as v2h; [jm][i] for this thread's slice
    v2h whh0[2][16], wih1[2][16], whh1[2][16];
#pragma unroll
    for (int i = 0; i < 16; ++i) {
        const int k = 32 * q + 2 * i;
#pragma unroll
        for (int m = 0; m < 2; ++m) {
            const int j = 2 * jg + m;
            whh0[m][i] = v2h{(_Float16)W_hh[k * HID + j],
                             (_Float16)W_hh[(k + 1) * HID + j]};
            wih1[m][i] = v2h{(_Float16)W_ih[HID * HID + k * HID + j],
                             (_Float16)W_ih[HID * HID + (k + 1) * HID + j]};
            whh1[m][i] = v2h{(_Float16)W_hh[HID * HID + k * HID + j],
                             (_Float16)W_hh[HID * HID + (k + 1) * HID + j]};
        }
    }
    const float b1K = bias[HID + jt] * LOG2E2;       // layer-1 bias (task col)

    __syncthreads();                                 // xids + zeroed h visible

    // Y-gather ring (depth 2) for this lane's task column
    _Float16 zA = Y[(size_t)xids[0] * HID + jt];
    _Float16 zB = Y[(size_t)xids[min(1, lenm1)] * HID + jt];

    int ph = 0, pf = 0;

    // tanh(z) with pre-scaled arg zK = z*2*log2(e): 1 - 2/(exp2(zK)+1)
#define TANH_PRE(ZK) (1.0f - 2.0f * fast_rcp(__builtin_amdgcn_exp2f(ZK) + 1.0f))

#define DO_PHASE(RD, WR, ZREG)                                              \
    {                                                                       \
        const uint4* h0p = (const uint4*)&h0h[RD][0] + q * 4;               \
        const uint4* h1p = (const uint4*)&h1h[RD][0] + q * 4;               \
        const float zcK = (float)ZREG * LOG2E2;                             \
        {                                                                   \
            const int tn = xids[min(ph + 2, lenm1)];                        \
            ZREG = Y[(size_t)tn * HID + jt];                                \
        }                                                                   \
        float a0_0 = 0.f, a0_1 = 0.f;   /* Whh0 . h0 for j0, j1 */          \
        float aA_0 = 0.f, aA_1 = 0.f;   /* Wih1 . h0 */                     \
        float aB_0 = 0.f, aB_1 = 0.f;   /* Whh1 . h1 */                     \
        _Pragma("unroll")                                                   \
        for (int c = 0; c < 4; ++c) {                                       \
            const uint4 hu = h0p[c];                                        \
            const uint4 gu = h1p[c];                                        \
            a0_0 = dot2(BCH(hu.x), whh0[0][4*c+0], a0_0);                   \
            a0_0 = dot2(BCH(hu.y), whh0[0][4*c+1], a0_0);                   \
            a0_0 = dot2(BCH(hu.z), whh0[0][4*c+2], a0_0);                   \
            a0_0 = dot2(BCH(hu.w), whh0[0][4*c+3], a0_0);                   \
            a0_1 = dot2(BCH(hu.x), whh0[1][4*c+0], a0_1);                   \
            a0_1 = dot2(BCH(hu.y), whh0[1][4*c+1], a0_1);                   \
            a0_1 = dot2(BCH(hu.z), whh0[1][4*c+2], a0_1);                   \
            a0_1 = dot2(BCH(hu.w), whh0[1][4*c+3], a0_1);                   \
            aA_0 = dot2(BCH(hu.x), wih1[0][4*c+0], aA_0);                   \
            aA_0 = dot2(BCH(hu.y), wih1[0][4*c+1], aA_0);                   \
            aA_0 = dot2(BCH(hu.z), wih1[0][4*c+2], aA_0);                   \
            aA_0 = dot2(BCH(hu.w), wih1[0][4*c+3], aA_0);                   \
            aA_1 = dot2(BCH(hu.x), wih1[1][4*c+0], aA_1);                   \
            aA_1 = dot2(BCH(hu.y), wih1[1][4*c+1], aA_1);                   \
            aA_1 = dot2(BCH(hu.z), wih1[1][4*c+2], aA_1);                   \
            aA_1 = dot2(BCH(hu.w), wih1[1][4*c+3], aA_1);                   \
            aB_0 = dot2(BCH(gu.x), whh1[0][4*c+0], aB_0);                   \
            aB_0 = dot2(BCH(gu.y), whh1[0][4*c+1], aB_0);                   \
            aB_0 = dot2(BCH(gu.z), whh1[0][4*c+2], aB_0);                   \
            aB_0 = dot2(BCH(gu.w), whh1[0][4*c+3], aB_0);                   \
            aB_1 = dot2(BCH(gu.x), whh1[1][4*c+0], aB_1);                   \
            aB_1 = dot2(BCH(gu.y), whh1[1][4*c+1], aB_1);                   \
            aB_1 = dot2(BCH(gu.z), whh1[1][4*c+2], aB_1);                   \
            aB_1 = dot2(BCH(gu.w), whh1[1][4*c+3], aB_1);                   \
        }                                                                   \
        float s0_0 = quad_reduce(a0_0);                                     \
        float s0_1 = quad_reduce(a0_1);                                     \
        float s1_0 = quad_reduce(aA_0 + aB_0);                              \
        float s1_1 = quad_reduce(aA_1 + aB_1);                              \
        const float sj  = jm  ? (isl1 ? s1_1 : s0_1) : (isl1 ? s1_0 : s0_0);\
        const float cj  = isl1 ? b1K : zcK;                                 \
        const float t   = TANH_PRE(__builtin_fmaf(sj, LOG2E2, cj));         \
        if (!isl1) { if (ph < len) h0h[WR][jt] = (_Float16)t; }             \
        else       { if (ph >= 1)  h1h[WR][jt] = (_Float16)t; }             \
        __syncthreads();                                                    \
    }

    for (;;) {
        DO_PHASE(0, 1, zA)
        ++ph;
        if (ph > len) { pf = 1; break; }
        DO_PHASE(1, 0, zB)
        ++ph;
        if (ph > len) { pf = 0; break; }
    }
#undef DO_PHASE
#undef TANH_PRE

    // classifier: out[b] = sigmoid(h1(len-1) . cls_w + cls_b)
    if (tid < HID) red[tid] = (float)h1h[pf][tid] * cls_w[tid];
    __syncthreads();
    if (tid == 0) {
        float s = 0.f;
        for (int i = 0; i < HID; ++i) s += red[i];
        s += cls_b[0];
        out[b] = fast_rcp(1.0f + __expf(-s));
    }
}

extern "C" void kernel_launch(void* const* d_in, const int* in_sizes, int n_in,
                              void* d_out, int out_size, void* d_ws, size_t ws_size,
                              hipStream_t stream) {
    const int*   x       = (const int*)  d_in[0];
    const int*   lengths = (const int*)  d_in[1];
    const float* emb     = (const float*)d_in[2];
    const float* W_ih    = (const float*)d_in[3];
    const float* W_hh    = (const float*)d_in[4];
    const float* bias    = (const float*)d_in[5];
    const float* cls_w   = (const float*)d_in[6];
    const float* cls_b   = (const float*)d_in[7];
    float*       out     = (float*)      d_out;

    _Float16* Yws = (_Float16*)d_ws;     // 50000*128*2 B = 12.8 MB

    emb_proj_kernel<<<2048, 512, 0, stream>>>(emb, W_ih, bias, Yws);
    rnn_dot2_kernel<<<BATCH, NTHR, 0, stream>>>(
        x, lengths, Yws, W_ih, W_hh, bias, cls_w, cls_b, out);
}